// Round 10
// baseline (445.008 us; speedup 1.0000x reference)
//
#include <hip/hip_runtime.h>
#include <hip/hip_bf16.h>

constexpr int Dn  = 3;
constexpr int Un  = 256;
constexpr int Hn  = 8;
constexpr int DHn = 32;
constexpr int Bn  = 128;
constexpr int Nn  = 128;
constexpr int En  = 512;
constexpr float BN_SCALE_C = 0.9995003746877732f; // 1/sqrt(1.001)

#define LB __launch_bounds__(256)
#define LB8 __launch_bounds__(512)

typedef short bf16x8 __attribute__((ext_vector_type(8)));
typedef unsigned short u16x8 __attribute__((ext_vector_type(8)));
typedef float f32x4 __attribute__((ext_vector_type(4)));
#define MFMA16(a, b, c) __builtin_amdgcn_mfma_f32_16x16x32_bf16(a, b, c, 0, 0, 0)

__device__ __forceinline__ void gload16(const void* g, void* l) {
  __builtin_amdgcn_global_load_lds(
      (const __attribute__((address_space(1))) void*)g,
      (__attribute__((address_space(3))) void*)l, 16, 0, 0);
}
__device__ __forceinline__ float sigm(float x) { return 1.f / (1.f + expf(-x)); }
__device__ __forceinline__ float bf2f(unsigned short u) {
  return __uint_as_float((unsigned)u << 16);
}

// ---------------------------------------------------------------- f32 -> bf16
__global__ LB void k_f2bf(const float* __restrict__ in,
                          __hip_bfloat16* __restrict__ out, int n) {
  int i = (blockIdx.x * 256 + threadIdx.x) * 4;
  if (i + 3 < n) {
    float4 v = *reinterpret_cast<const float4*>(in + i);
    out[i + 0] = __float2bfloat16(v.x);
    out[i + 1] = __float2bfloat16(v.y);
    out[i + 2] = __float2bfloat16(v.z);
    out[i + 3] = __float2bfloat16(v.w);
  }
}

// --------------------------- weight prep: transpose + bf16 (B^T layouts)
__global__ LB void k_prep_edge(const float* __restrict__ W,  // (D,768,256)
                               __hip_bfloat16* __restrict__ Wt) { // (D,256,768)
  int idx = blockIdx.x * 256 + threadIdx.x;
  int d = idx / (Un * 3 * Un);
  int rem = idx % (Un * 3 * Un);
  int n = rem / (3 * Un);
  int k = rem % (3 * Un);
  Wt[idx] = __float2bfloat16(W[(size_t)d * 3 * Un * Un + (size_t)k * Un + n]);
}

__global__ LB void k_prep_hn(const float* __restrict__ Wg,   // (D,256,256)
                             const float* __restrict__ Wn,   // (D,256,256)
                             __hip_bfloat16* __restrict__ Wt) { // (D,512,256)
  int idx = blockIdx.x * 256 + threadIdx.x;
  int d = idx / (512 * 256);
  int rem = idx % (512 * 256);
  int n = rem / 256;
  int k = rem % 256;
  float v = (n < 256) ? Wg[(size_t)d * 65536 + k * 256 + n]
                      : Wn[(size_t)d * 65536 + k * 256 + (n - 256)];
  Wt[idx] = __float2bfloat16(v);
}

// B2[j2][k], j2 in [0,768): z (full K), r (full K), xh/uh time-shared.
__global__ LB void k_prep_gru2(const float* __restrict__ W,   // (D,256,768)
                               const float* __restrict__ U,   // (D,256,768)
                               __hip_bfloat16* __restrict__ Wt) { // (D,768,512)
  int idx = blockIdx.x * 256 + threadIdx.x;
  int d = idx / (768 * 512);
  int rem = idx % (768 * 512);
  int j2 = rem >> 9;
  int k = rem & 511;
  const size_t wb = (size_t)d * 196608;
  float v = (k < 256) ? W[wb + k * 768 + j2] : U[wb + (k - 256) * 768 + j2];
  Wt[idx] = __float2bfloat16(v);
}

// ============== fat kernel: edge GEMM (+fused elog) and h/n_up GEMM =========
// blocks [0,512): edge M=65536,K=768,N=256 tile 128x256, then elog tail
// blocks [512,768): hn  M=16384,K=256,N=512 tile 128x256
__global__ LB8 void k_edge_hn(const __hip_bfloat16* __restrict__ nodes,
                              const __hip_bfloat16* __restrict__ edges,
                              const int* __restrict__ eidx,
                              const __hip_bfloat16* __restrict__ Wt_e, // (256,768)
                              const float* __restrict__ bias,
                              const float* __restrict__ gamma,
                              const float* __restrict__ beta,
                              const float* __restrict__ a_gat,         // (H,320)
                              float* __restrict__ elog,                // (B*E,8)
                              __hip_bfloat16* __restrict__ e_up,
                              const __hip_bfloat16* __restrict__ Wt_hn, // (512,256)
                              const float* __restrict__ nb,
                              const float* __restrict__ ng,
                              const float* __restrict__ nbe,
                              __hip_bfloat16* __restrict__ h_bf,
                              __hip_bfloat16* __restrict__ nupb) {
  __shared__ __align__(16) short As[128 * 64];   // 16 KB
  __shared__ __align__(16) short Bs[256 * 64];   // 32 KB
  const int tid = threadIdx.x, lane = tid & 63;
  const int w = tid >> 6, wr = w >> 2, wc = w & 3;   // 2 x 4 waves

  if (blockIdx.x < 512) {
    // ------------------------------- edge part
    const int bid = blockIdx.x;
    const int wgid = (bid & 7) * 64 + (bid >> 3);    // XCD-chunked
    const int row0 = wgid * 128;
    const __hip_bfloat16 *pa0[2], *pa1[2], *pa2[2], *pb[4];
    int sxa[2], sxb[4];
#pragma unroll
    for (int i = 0; i < 2; ++i) {
      int c = i * 512 + tid, row = c >> 3, slot = c & 7;
      int R = row0 + row, b = R >> 9, e = R & 511;
      int tt = eidx[(b * En + e) * 2 + 0];
      int ss = eidx[(b * En + e) * 2 + 1];
      pa0[i] = nodes + (size_t)(b * Nn + ss) * Un;
      pa1[i] = nodes + (size_t)(b * Nn + tt) * Un;
      pa2[i] = edges + (size_t)(b * En + e) * Un;
      sxa[i] = (slot ^ (row & 7)) * 8;
    }
#pragma unroll
    for (int i = 0; i < 4; ++i) {
      int c = i * 512 + tid, j = c >> 3, slot = c & 7;
      pb[i] = Wt_e + (size_t)j * 768;
      sxb[i] = (slot ^ (j & 7)) * 8;
    }
    f32x4 acc[4][4] = {};
    const int ldsb = (tid & 448) * 16;
    for (int kt = 0; kt < 768; kt += 64) {
      const int region = kt >> 8, koff = kt & 255;
#pragma unroll
      for (int i = 0; i < 2; ++i) {
        const __hip_bfloat16* s = (region == 0) ? pa0[i] : (region == 1 ? pa1[i] : pa2[i]);
        gload16(s + koff + sxa[i], (char*)As + i * 8192 + ldsb);
      }
#pragma unroll
      for (int i = 0; i < 4; ++i)
        gload16(pb[i] + kt + sxb[i], (char*)Bs + i * 8192 + ldsb);
      __syncthreads();
#pragma unroll
      for (int ks = 0; ks < 2; ++ks) {
        const int lc = ks * 4 + (lane >> 4);
        bf16x8 af[4], bfv[4];
#pragma unroll
        for (int mi = 0; mi < 4; ++mi) {
          int row = wr * 64 + mi * 16 + (lane & 15);
          af[mi] = *(const bf16x8*)((const char*)As + row * 128 + ((lc ^ (row & 7)) << 4));
        }
#pragma unroll
        for (int ni = 0; ni < 4; ++ni) {
          int col = wc * 64 + ni * 16 + (lane & 15);
          bfv[ni] = *(const bf16x8*)((const char*)Bs + col * 128 + ((lc ^ (col & 7)) << 4));
        }
#pragma unroll
        for (int mi = 0; mi < 4; ++mi)
#pragma unroll
          for (int ni = 0; ni < 4; ++ni)
            acc[mi][ni] = MFMA16(af[mi], bfv[ni], acc[mi][ni]);
      }
      __syncthreads();
    }
#pragma unroll
    for (int mi = 0; mi < 4; ++mi)
#pragma unroll
      for (int ni = 0; ni < 4; ++ni) {
        int C = wc * 64 + ni * 16 + (lane & 15);
        float gs = gamma[C] * BN_SCALE_C, bt = beta[C], bi = bias[C];
#pragma unroll
        for (int r = 0; r < 4; ++r) {
          int R = row0 + wr * 64 + mi * 16 + (lane >> 4) * 4 + r;
          float v = acc[mi][ni][r] + bi;
          v = fmaxf(v, 0.f) * gs + bt;
          e_up[(size_t)R * Un + C] = __float2bfloat16(v);
        }
      }
    // ---------- fused elog tail: elog[r,h] = e_up[r,:] . a_gat[h,64:320]
    __threadfence_block();
    float* s_a = (float*)As;   // reuse As (8 KB of 16 KB) — K-loop done
    for (int l = tid; l < 8 * 256; l += 512)
      s_a[l] = a_gat[(l >> 8) * 320 + 64 + (l & 255)];
    __syncthreads();
    {
      const int row = row0 + (tid >> 2);
      const int l4 = tid & 3;
      const u16x8* er = (const u16x8*)(e_up + (size_t)row * 256 + l4 * 64);
      float a2[8] = {};
#pragma unroll
      for (int c = 0; c < 8; ++c) {
        u16x8 v = er[c];
#pragma unroll
        for (int j = 0; j < 8; ++j) {
          float f = bf2f(v[j]);
          int k = l4 * 64 + c * 8 + j;
#pragma unroll
          for (int hh = 0; hh < 8; ++hh) a2[hh] += f * s_a[hh * 256 + k];
        }
      }
#pragma unroll
      for (int hh = 0; hh < 8; ++hh) {
        a2[hh] += __shfl_xor(a2[hh], 1);
        a2[hh] += __shfl_xor(a2[hh], 2);
      }
      elog[(size_t)row * 8 + 2 * l4]     = a2[2 * l4];
      elog[(size_t)row * 8 + 2 * l4 + 1] = a2[2 * l4 + 1];
    }
  } else {
    // ------------------------------- hn part
    const int bid = blockIdx.x - 512;
    const int wgid = (bid & 7) * 32 + (bid >> 3);    // XCD-chunked
    const int row0 = (wgid >> 1) * 128, col0 = (wgid & 1) * 256;
    const __hip_bfloat16 *pa[2], *pb[4];
    int sxa[2], sxb[4];
#pragma unroll
    for (int i = 0; i < 2; ++i) {
      int c = i * 512 + tid, row = c >> 3, slot = c & 7;
      pa[i] = nodes + (size_t)(row0 + row) * Un;
      sxa[i] = (slot ^ (row & 7)) * 8;
    }
#pragma unroll
    for (int i = 0; i < 4; ++i) {
      int c = i * 512 + tid, j = c >> 3, slot = c & 7;
      pb[i] = Wt_hn + (size_t)(col0 + j) * Un;
      sxb[i] = (slot ^ (j & 7)) * 8;
    }
    f32x4 acc[4][4] = {};
    const int ldsb = (tid & 448) * 16;
    for (int kt = 0; kt < 256; kt += 64) {
#pragma unroll
      for (int i = 0; i < 2; ++i)
        gload16(pa[i] + kt + sxa[i], (char*)As + i * 8192 + ldsb);
#pragma unroll
      for (int i = 0; i < 4; ++i)
        gload16(pb[i] + kt + sxb[i], (char*)Bs + i * 8192 + ldsb);
      __syncthreads();
#pragma unroll
      for (int ks = 0; ks < 2; ++ks) {
        const int lc = ks * 4 + (lane >> 4);
        bf16x8 af[4], bfv[4];
#pragma unroll
        for (int mi = 0; mi < 4; ++mi) {
          int row = wr * 64 + mi * 16 + (lane & 15);
          af[mi] = *(const bf16x8*)((const char*)As + row * 128 + ((lc ^ (row & 7)) << 4));
        }
#pragma unroll
        for (int ni = 0; ni < 4; ++ni) {
          int col = wc * 64 + ni * 16 + (lane & 15);
          bfv[ni] = *(const bf16x8*)((const char*)Bs + col * 128 + ((lc ^ (col & 7)) << 4));
        }
#pragma unroll
        for (int mi = 0; mi < 4; ++mi)
#pragma unroll
          for (int ni = 0; ni < 4; ++ni)
            acc[mi][ni] = MFMA16(af[mi], bfv[ni], acc[mi][ni]);
      }
      __syncthreads();
    }
    const bool is_h = (col0 < 256);
#pragma unroll
    for (int mi = 0; mi < 4; ++mi)
#pragma unroll
      for (int ni = 0; ni < 4; ++ni) {
        int c2 = wc * 64 + ni * 16 + (lane & 15);
#pragma unroll
        for (int r = 0; r < 4; ++r) {
          int R = row0 + wr * 64 + mi * 16 + (lane >> 4) * 4 + r;
          float v = acc[mi][ni][r];
          if (is_h) {
            h_bf[(size_t)R * Un + c2] = __float2bfloat16(v);
          } else {
            v += nb[c2];
            v = fmaxf(v, 0.f) * (ng[c2] * BN_SCALE_C) + nbe[c2];
            nupb[(size_t)R * Un + c2] = __float2bfloat16(v);
          }
        }
      }
  }
}

// ------------- fused GRU v2: zero-free B (768,512), grid 1024 1D swizzled
__global__ LB void k_gru_mfma2(const __hip_bfloat16* __restrict__ attb,
                               const __hip_bfloat16* __restrict__ nupb,
                               const __hip_bfloat16* __restrict__ Wt,  // (768,512)
                               const float* __restrict__ bg,           // (768)
                               __hip_bfloat16* __restrict__ nodes_out) {
  __shared__ __align__(16) short As[128 * 64];
  __shared__ __align__(16) short Bs[96 * 64];
  const int tid = threadIdx.x, lane = tid & 63;
  const int w = tid >> 6, wr = w >> 1, wc = w & 1;
  const int bid = blockIdx.x;
  const int wgid = (bid & 7) * 128 + (bid >> 3);   // XCD-chunked
  const int row0 = (wgid >> 3) * 128, c0 = (wgid & 7) * 32;
  const __hip_bfloat16 *paA[4], *paN[4], *pb[3];
  int sxa[4], sxb[3];
#pragma unroll
  for (int i = 0; i < 4; ++i) {
    int c = i * 256 + tid, row = c >> 3, slot = c & 7;
    paA[i] = attb + (size_t)(row0 + row) * Un;
    paN[i] = nupb + (size_t)(row0 + row) * Un;
    sxa[i] = (slot ^ (row & 7)) * 8;
  }
#pragma unroll
  for (int i = 0; i < 3; ++i) {
    int l = i * 256 + tid, j = l >> 3, slot = l & 7;
    int grow = (j < 32) ? (c0 + j) : (j < 64) ? (256 + c0 + (j - 32))
                                              : (512 + c0 + (j - 64));
    pb[i] = Wt + (size_t)grow * 512;
    sxb[i] = (slot ^ (j & 7)) * 8;
  }
  f32x4 acc[4][4] = {};   // [z,r,xh,uh][mi]
  const int ldsb = (tid & 192) * 16;
  for (int kt = 0; kt < 512; kt += 64) {
    const int koff = kt & 255;
    const bool rA = kt < 256;
#pragma unroll
    for (int i = 0; i < 4; ++i) {
      const __hip_bfloat16* s = rA ? paA[i] : paN[i];
      gload16(s + koff + sxa[i], (char*)As + i * 4096 + ldsb);
    }
#pragma unroll
    for (int i = 0; i < 3; ++i)
      gload16(pb[i] + kt + sxb[i], (char*)Bs + i * 4096 + ldsb);
    __syncthreads();
    const int g2 = rA ? 2 : 3;
#pragma unroll
    for (int ks = 0; ks < 2; ++ks) {
      const int lc = ks * 4 + (lane >> 4);
      bf16x8 af[4], bv[3];
      const int jj = wc * 16 + (lane & 15);
      const int jsw = (lc ^ (jj & 7)) << 4;
      bv[0] = *(const bf16x8*)((const char*)Bs + jj * 128 + jsw);
      bv[1] = *(const bf16x8*)((const char*)Bs + (32 + jj) * 128 + jsw);
      bv[2] = *(const bf16x8*)((const char*)Bs + (64 + jj) * 128 + jsw);
#pragma unroll
      for (int mi = 0; mi < 4; ++mi) {
        int row = wr * 64 + mi * 16 + (lane & 15);
        af[mi] = *(const bf16x8*)((const char*)As + row * 128 + ((lc ^ (row & 7)) << 4));
      }
#pragma unroll
      for (int mi = 0; mi < 4; ++mi) {
        acc[0][mi] = MFMA16(af[mi], bv[0], acc[0][mi]);
        acc[1][mi] = MFMA16(af[mi], bv[1], acc[1][mi]);
        acc[g2][mi] = MFMA16(af[mi], bv[2], acc[g2][mi]);
      }
    }
    __syncthreads();
  }
  {
    const int c = c0 + wc * 16 + (lane & 15);
    const float bz = bg[c], br = bg[256 + c], bh = bg[512 + c];
    const unsigned short* nu_u = (const unsigned short*)nupb;
#pragma unroll
    for (int mi = 0; mi < 4; ++mi)
#pragma unroll
      for (int r = 0; r < 4; ++r) {
        int R = row0 + wr * 64 + mi * 16 + (lane >> 4) * 4 + r;
        float z  = sigm(acc[0][mi][r] + bz);
        float rr = sigm(acc[1][mi][r] + br);
        float hh = tanhf(acc[2][mi][r] + bh + rr * acc[3][mi][r]);
        float nu = bf2f(nu_u[(size_t)R * Un + c]);
        nodes_out[(size_t)R * Un + c] = __float2bfloat16(z * nu + (1.f - z) * hh);
      }
  }
}

// ---------------- GAT v3: fused nlog + CSR softmax + LDS-h aggregate (bf16 h)
__global__ LB void k_gat3(const __hip_bfloat16* __restrict__ h,  // (B*N,256) bf16
                          const float* __restrict__ elog,        // (B*E,8)
                          const int* __restrict__ eidx,
                          const float* __restrict__ a_gat,       // (H,320)
                          const float* __restrict__ b_gat,       // (H)
                          __hip_bfloat16* __restrict__ att_bf) { // (B*N,256)
  const int b = blockIdx.x, hg = blockIdx.y;
  __shared__ int s_tgt[En], s_src[En];
  __shared__ float s_at[4][32], s_as[4][32];
  __shared__ float s_lt[Nn][4], s_ls[Nn][4];
  __shared__ float s_L[En][4];
  __shared__ int s_cnt[Nn], s_start[Nn], s_cur[Nn];
  __shared__ short s_ord[En];
  __shared__ float s_bg[4];
  __shared__ __align__(16) unsigned short hl[Nn][136];
  const int tid = threadIdx.x;
  if (tid < 4) s_bg[tid] = b_gat[hg * 4 + tid];
  if (tid < 128) {
    int q = tid >> 5, d = tid & 31;
    s_at[q][d] = a_gat[(hg * 4 + q) * 320 + d];
    s_as[q][d] = a_gat[(hg * 4 + q) * 320 + 32 + d];
  }
  for (int e = tid; e < En; e += 256) {
    s_tgt[e] = eidx[(b * En + e) * 2 + 0];
    s_src[e] = eidx[(b * En + e) * 2 + 1];
  }
  for (int l = tid; l < Nn; l += 256) s_cnt[l] = 0;
  for (int l = tid; l < En * 4; l += 256) {
    int e = l >> 2, q = l & 3;
    s_L[e][q] = elog[(size_t)(b * En + e) * 8 + hg * 4 + q];
  }
  const unsigned short* hu = (const unsigned short*)h;
  for (int l = tid; l < Nn * 16; l += 256) {
    int row = l >> 4, c8 = l & 15;
    u16x8 v = *(const u16x8*)(hu + (size_t)(b * Nn + row) * Un + hg * 128 + c8 * 8);
    *(u16x8*)&hl[row][c8 * 8] = v;
  }
  __syncthreads();
  for (int p = tid; p < Nn * 4; p += 256) {
    int n = p >> 2, q = p & 3;
    const unsigned short* hr = &hl[n][q * 32];
    float lt = 0.f, ls = 0.f;
#pragma unroll
    for (int c8 = 0; c8 < 4; ++c8) {
      u16x8 v = *(const u16x8*)(hr + c8 * 8);
#pragma unroll
      for (int j = 0; j < 8; ++j) {
        float f = bf2f(v[j]);
        int d = c8 * 8 + j;
        lt += f * s_at[q][d];
        ls += f * s_as[q][d];
      }
    }
    s_lt[n][q] = lt; s_ls[n][q] = ls;
  }
  for (int e = tid; e < En; e += 256) atomicAdd(&s_cnt[s_tgt[e]], 1);
  __syncthreads();
  if (tid == 0) {
    int acc = 0;
    for (int n = 0; n < Nn; ++n) { s_start[n] = acc; s_cur[n] = acc; acc += s_cnt[n]; }
  }
  __syncthreads();
  for (int e = tid; e < En; e += 256) {
    int pos = atomicAdd(&s_cur[s_tgt[e]], 1);
    s_ord[pos] = (short)e;
  }
  for (int l = tid; l < En * 4; l += 256) {
    int e = l >> 2, q = l & 3;
    float v = s_lt[s_tgt[e]][q] + s_ls[s_src[e]][q] + s_L[e][q] + s_bg[q];
    v = (v > 0.f) ? v : 0.2f * v;
    s_L[e][q] = v;
  }
  __syncthreads();
  for (int p = tid; p < Nn * 4; p += 256) {
    const int n = p >> 2, q = p & 3;
    const int st = s_start[n], cn = s_cnt[n];
    float m = -1e9f;
    for (int i = 0; i < cn; ++i) m = fmaxf(m, s_L[s_ord[st + i]][q]);
    float den = 1e-9f;
    for (int i = 0; i < cn; ++i) {
      const int e = s_ord[st + i];
      float ex = expf(s_L[e][q] - m);
      s_L[e][q] = ex;
      den += ex;
    }
    const float inv = 1.f / den;
    float acc[32] = {};
    for (int i = 0; i < cn; ++i) {
      const int e = s_ord[st + i];
      const float wgt = s_L[e][q] * inv;
      const unsigned short* hs = &hl[s_src[e]][q * 32];
#pragma unroll
      for (int c8 = 0; c8 < 4; ++c8) {
        u16x8 v = *(const u16x8*)(hs + c8 * 8);
#pragma unroll
        for (int j = 0; j < 8; ++j) acc[c8 * 8 + j] += wgt * bf2f(v[j]);
      }
    }
    __hip_bfloat16* ob = att_bf + (size_t)(b * Nn + n) * Un + (hg * 4 + q) * DHn;
#pragma unroll
    for (int d = 0; d < 32; ++d) ob[d] = __float2bfloat16(fmaxf(acc[d], 0.f));
  }
}

// -------------------------------------------------- mean-pool + MLP head
__global__ LB void k_pool(const __hip_bfloat16* __restrict__ nodes,
                          const float* __restrict__ Wp1, const float* __restrict__ bp1,
                          const float* __restrict__ Wp2, const float* __restrict__ bp2,
                          float* __restrict__ out) {
  const int b = blockIdx.x, tid = threadIdx.x;
  __shared__ float e0[256], e1[256];
  float s = 0.f;
  for (int n = 0; n < Nn; ++n) s += __bfloat162float(nodes[(size_t)(b * Nn + n) * Un + tid]);
  e0[tid] = s * (1.f / Nn);
  __syncthreads();
  float a1 = bp1[tid];
  for (int k = 0; k < 256; ++k) a1 += e0[k] * Wp1[k * 256 + tid];
  e1[tid] = fmaxf(a1, 0.f);
  __syncthreads();
  if (tid < 128) {
    float a2 = bp2[tid];
    for (int k = 0; k < 256; ++k) a2 += e1[k] * Wp2[k * 128 + tid];
    a2 = fmaxf(a2, 0.f);
    out[b * 128 + tid] = a2;
    out[Bn * 128 + b * 256 + tid] = a2;
    out[Bn * 128 + b * 256 + 128 + tid] = a2;
  }
}

extern "C" void kernel_launch(void* const* d_in, const int* in_sizes, int n_in,
                              void* d_out, int out_size, void* d_ws, size_t ws_size,
                              hipStream_t stream) {
  const float* node_attr = (const float*)d_in[0];
  const float* edge_attr = (const float*)d_in[1];
  const int*   eidx      = (const int*)d_in[2];
  const float* W_edge    = (const float*)d_in[3];
  const float* b_edge    = (const float*)d_in[4];
  const float* gamma_e   = (const float*)d_in[5];
  const float* beta_e    = (const float*)d_in[6];
  const float* W_node    = (const float*)d_in[7];
  const float* b_node    = (const float*)d_in[8];
  const float* gamma_n   = (const float*)d_in[9];
  const float* beta_n    = (const float*)d_in[10];
  const float* W_gat     = (const float*)d_in[11];
  const float* a_gat     = (const float*)d_in[12];
  const float* b_gat     = (const float*)d_in[13];
  const float* W_gru     = (const float*)d_in[14];
  const float* U_gru     = (const float*)d_in[15];
  const float* b_gru     = (const float*)d_in[16];
  const float* W_p1      = (const float*)d_in[17];
  const float* b_p1      = (const float*)d_in[18];
  const float* W_p2      = (const float*)d_in[19];
  const float* b_p2      = (const float*)d_in[20];

  char* p = (char*)d_ws;
  auto alloc = [&](size_t bytes) { char* q = p; p += (bytes + 255) & ~255ull; return q; };
  const size_t NODE_EL = (size_t)Bn * Nn * Un;   // 4,194,304
  const size_t EDGE_EL = (size_t)Bn * En * Un;   // 16,777,216
  __hip_bfloat16* nodes_bf = (__hip_bfloat16*)alloc(NODE_EL * 2);
  __hip_bfloat16* h_bf   = (__hip_bfloat16*)alloc(NODE_EL * 2);
  __hip_bfloat16* nup_bf = (__hip_bfloat16*)alloc(NODE_EL * 2);
  __hip_bfloat16* att_bf = (__hip_bfloat16*)alloc(NODE_EL * 2);
  float* elog   = (float*)alloc((size_t)Bn * En * 8 * 4);
  __hip_bfloat16* edges_a = (__hip_bfloat16*)alloc(EDGE_EL * 2);
  __hip_bfloat16* edges_b = (__hip_bfloat16*)alloc(EDGE_EL * 2);
  __hip_bfloat16* Wt_e   = (__hip_bfloat16*)alloc((size_t)Dn * 256 * 768 * 2);
  __hip_bfloat16* Wt_hn  = (__hip_bfloat16*)alloc((size_t)Dn * 512 * 256 * 2);
  __hip_bfloat16* Wt_gru = (__hip_bfloat16*)alloc((size_t)Dn * 768 * 512 * 2);

  k_f2bf<<<(int)(EDGE_EL / 1024), 256, 0, stream>>>(edge_attr, edges_a, (int)EDGE_EL);
  k_f2bf<<<(int)(NODE_EL / 1024), 256, 0, stream>>>(node_attr, nodes_bf, (int)NODE_EL);
  k_prep_edge<<<(Dn * 256 * 768) / 256, 256, 0, stream>>>(W_edge, Wt_e);
  k_prep_hn<<<(Dn * 512 * 256) / 256, 256, 0, stream>>>(W_gat, W_node, Wt_hn);
  k_prep_gru2<<<(Dn * 768 * 512) / 256, 256, 0, stream>>>(W_gru, U_gru, Wt_gru);

  __hip_bfloat16* ein = edges_a;
  __hip_bfloat16* eout = edges_b;
  for (int d = 0; d < Dn; ++d) {
    k_edge_hn<<<768, 512, 0, stream>>>(
        nodes_bf, ein, eidx, Wt_e + (size_t)d * 256 * 768, b_edge + d * Un,
        gamma_e + d * Un, beta_e + d * Un, a_gat + (size_t)d * Hn * 320, elog, eout,
        Wt_hn + (size_t)d * 512 * 256, b_node + d * Un,
        gamma_n + d * Un, beta_n + d * Un, h_bf, nup_bf);
    k_gat3<<<dim3(Bn, 2), 256, 0, stream>>>(
        h_bf, elog, eidx, a_gat + (size_t)d * Hn * 320, b_gat + d * Hn, att_bf);
    k_gru_mfma2<<<1024, 256, 0, stream>>>(
        att_bf, nup_bf, Wt_gru + (size_t)d * 768 * 512, b_gru + d * 3 * Un,
        nodes_bf);
    __hip_bfloat16* t = ein; ein = eout; eout = t;
  }
  k_pool<<<Bn, 256, 0, stream>>>(nodes_bf, W_p1, b_p1, W_p2, b_p2, (float*)d_out);
}

// Round 11
// 369.421 us; speedup vs baseline: 1.2046x; 1.2046x over previous
//
#include <hip/hip_runtime.h>
#include <hip/hip_bf16.h>

constexpr int Dn  = 3;
constexpr int Un  = 256;
constexpr int Hn  = 8;
constexpr int DHn = 32;
constexpr int Bn  = 128;
constexpr int Nn  = 128;
constexpr int En  = 512;
constexpr float BN_SCALE_C = 0.9995003746877732f; // 1/sqrt(1.001)

#define LB __launch_bounds__(256)
#define LB8 __launch_bounds__(512)

typedef short bf16x8 __attribute__((ext_vector_type(8)));
typedef unsigned short u16x8 __attribute__((ext_vector_type(8)));
typedef float f32x4 __attribute__((ext_vector_type(4)));
#define MFMA16(a, b, c) __builtin_amdgcn_mfma_f32_16x16x32_bf16(a, b, c, 0, 0, 0)

__device__ __forceinline__ void gload16(const void* g, void* l) {
  __builtin_amdgcn_global_load_lds(
      (const __attribute__((address_space(1))) void*)g,
      (__attribute__((address_space(3))) void*)l, 16, 0, 0);
}
__device__ __forceinline__ float sigm(float x) { return 1.f / (1.f + expf(-x)); }
__device__ __forceinline__ float bf2f(unsigned short u) {
  return __uint_as_float((unsigned)u << 16);
}

// ---------------------------------------------------------------- f32 -> bf16
__global__ LB void k_f2bf(const float* __restrict__ in,
                          __hip_bfloat16* __restrict__ out, int n) {
  int i = (blockIdx.x * 256 + threadIdx.x) * 4;
  if (i + 3 < n) {
    float4 v = *reinterpret_cast<const float4*>(in + i);
    out[i + 0] = __float2bfloat16(v.x);
    out[i + 1] = __float2bfloat16(v.y);
    out[i + 2] = __float2bfloat16(v.z);
    out[i + 3] = __float2bfloat16(v.w);
  }
}

// --------------------------- weight prep: transpose + bf16 (B^T layouts)
__global__ LB void k_prep_edge(const float* __restrict__ W,  // (D,768,256)
                               __hip_bfloat16* __restrict__ Wt) { // (D,256,768)
  int idx = blockIdx.x * 256 + threadIdx.x;
  int d = idx / (Un * 3 * Un);
  int rem = idx % (Un * 3 * Un);
  int n = rem / (3 * Un);
  int k = rem % (3 * Un);
  Wt[idx] = __float2bfloat16(W[(size_t)d * 3 * Un * Un + (size_t)k * Un + n]);
}

__global__ LB void k_prep_hn(const float* __restrict__ Wg,   // (D,256,256)
                             const float* __restrict__ Wn,   // (D,256,256)
                             __hip_bfloat16* __restrict__ Wt) { // (D,512,256)
  int idx = blockIdx.x * 256 + threadIdx.x;
  int d = idx / (512 * 256);
  int rem = idx % (512 * 256);
  int n = rem / 256;
  int k = rem % 256;
  float v = (n < 256) ? Wg[(size_t)d * 65536 + k * 256 + n]
                      : Wn[(size_t)d * 65536 + k * 256 + (n - 256)];
  Wt[idx] = __float2bfloat16(v);
}

// B2[j2][k], j2 in [0,768): z (full K), r (full K), xh/uh time-shared.
__global__ LB void k_prep_gru2(const float* __restrict__ W,   // (D,256,768)
                               const float* __restrict__ U,   // (D,256,768)
                               __hip_bfloat16* __restrict__ Wt) { // (D,768,512)
  int idx = blockIdx.x * 256 + threadIdx.x;
  int d = idx / (768 * 512);
  int rem = idx % (768 * 512);
  int j2 = rem >> 9;
  int k = rem & 511;
  const size_t wb = (size_t)d * 196608;
  float v = (k < 256) ? W[wb + k * 768 + j2] : U[wb + (k - 256) * 768 + j2];
  Wt[idx] = __float2bfloat16(v);
}

// ---------------- MFMA edge GEMM (M=65536,K=768,N=256), 8 waves, 128x256 tile
__global__ LB8 void k_edge_mfma(const __hip_bfloat16* __restrict__ nodes,
                                const __hip_bfloat16* __restrict__ edges,
                                const int* __restrict__ eidx,
                                const __hip_bfloat16* __restrict__ Wt, // (256,768)
                                const float* __restrict__ bias,
                                const float* __restrict__ gamma,
                                const float* __restrict__ beta,
                                __hip_bfloat16* __restrict__ e_up) {
  __shared__ __align__(16) short As[128 * 64];   // 16 KB
  __shared__ __align__(16) short Bs[256 * 64];   // 32 KB
  const int tid = threadIdx.x, lane = tid & 63;
  const int w = tid >> 6, wr = w >> 2, wc = w & 3;   // 2 x 4 waves
  const int bid = blockIdx.x;
  const int wgid = (bid & 7) * 64 + (bid >> 3);      // XCD-chunked
  const int row0 = wgid * 128;
  const __hip_bfloat16 *pa0[2], *pa1[2], *pa2[2], *pb[4];
  int sxa[2], sxb[4];
#pragma unroll
  for (int i = 0; i < 2; ++i) {
    int c = i * 512 + tid, row = c >> 3, slot = c & 7;
    int R = row0 + row, b = R >> 9, e = R & 511;
    int tt = eidx[(b * En + e) * 2 + 0];
    int ss = eidx[(b * En + e) * 2 + 1];
    pa0[i] = nodes + (size_t)(b * Nn + ss) * Un;
    pa1[i] = nodes + (size_t)(b * Nn + tt) * Un;
    pa2[i] = edges + (size_t)(b * En + e) * Un;
    sxa[i] = (slot ^ (row & 7)) * 8;
  }
#pragma unroll
  for (int i = 0; i < 4; ++i) {
    int c = i * 512 + tid, j = c >> 3, slot = c & 7;
    pb[i] = Wt + (size_t)j * 768;
    sxb[i] = (slot ^ (j & 7)) * 8;
  }
  f32x4 acc[4][4] = {};
  const int ldsb = (tid & 448) * 16;   // 64-lane-group uniform base
  for (int kt = 0; kt < 768; kt += 64) {
    const int region = kt >> 8, koff = kt & 255;
#pragma unroll
    for (int i = 0; i < 2; ++i) {
      const __hip_bfloat16* s = (region == 0) ? pa0[i] : (region == 1 ? pa1[i] : pa2[i]);
      gload16(s + koff + sxa[i], (char*)As + i * 8192 + ldsb);
    }
#pragma unroll
    for (int i = 0; i < 4; ++i)
      gload16(pb[i] + kt + sxb[i], (char*)Bs + i * 8192 + ldsb);
    __syncthreads();
#pragma unroll
    for (int ks = 0; ks < 2; ++ks) {
      const int lc = ks * 4 + (lane >> 4);
      bf16x8 af[4], bfv[4];
#pragma unroll
      for (int mi = 0; mi < 4; ++mi) {
        int row = wr * 64 + mi * 16 + (lane & 15);
        af[mi] = *(const bf16x8*)((const char*)As + row * 128 + ((lc ^ (row & 7)) << 4));
      }
#pragma unroll
      for (int ni = 0; ni < 4; ++ni) {
        int col = wc * 64 + ni * 16 + (lane & 15);
        bfv[ni] = *(const bf16x8*)((const char*)Bs + col * 128 + ((lc ^ (col & 7)) << 4));
      }
#pragma unroll
      for (int mi = 0; mi < 4; ++mi)
#pragma unroll
        for (int ni = 0; ni < 4; ++ni)
          acc[mi][ni] = MFMA16(af[mi], bfv[ni], acc[mi][ni]);
    }
    __syncthreads();
  }
#pragma unroll
  for (int mi = 0; mi < 4; ++mi)
#pragma unroll
    for (int ni = 0; ni < 4; ++ni) {
      int C = wc * 64 + ni * 16 + (lane & 15);
      float gs = gamma[C] * BN_SCALE_C, bt = beta[C], bi = bias[C];
#pragma unroll
      for (int r = 0; r < 4; ++r) {
        int R = row0 + wr * 64 + mi * 16 + (lane >> 4) * 4 + r;
        float v = acc[mi][ni][r] + bi;
        v = fmaxf(v, 0.f) * gs + bt;
        e_up[(size_t)R * Un + C] = __float2bfloat16(v);
      }
    }
}

// ------------- MFMA h/n_up GEMM (M=16384,K=256,N=512), 8 waves, 128x256 tile
__global__ LB8 void k_hn_mfma(const __hip_bfloat16* __restrict__ A,
                              const __hip_bfloat16* __restrict__ Wt, // (512,256)
                              const float* __restrict__ nb,
                              const float* __restrict__ ng,
                              const float* __restrict__ nbe,
                              __hip_bfloat16* __restrict__ h_bf,
                              __hip_bfloat16* __restrict__ nupb) {
  __shared__ __align__(16) short As[128 * 64];
  __shared__ __align__(16) short Bs[256 * 64];
  const int tid = threadIdx.x, lane = tid & 63;
  const int w = tid >> 6, wr = w >> 2, wc = w & 3;
  const int bid = blockIdx.x;
  const int wgid = (bid & 7) * 32 + (bid >> 3);      // XCD-chunked
  const int row0 = (wgid >> 1) * 128, col0 = (wgid & 1) * 256;
  const __hip_bfloat16 *pa[2], *pb[4];
  int sxa[2], sxb[4];
#pragma unroll
  for (int i = 0; i < 2; ++i) {
    int c = i * 512 + tid, row = c >> 3, slot = c & 7;
    pa[i] = A + (size_t)(row0 + row) * Un;
    sxa[i] = (slot ^ (row & 7)) * 8;
  }
#pragma unroll
  for (int i = 0; i < 4; ++i) {
    int c = i * 512 + tid, j = c >> 3, slot = c & 7;
    pb[i] = Wt + (size_t)(col0 + j) * Un;
    sxb[i] = (slot ^ (j & 7)) * 8;
  }
  f32x4 acc[4][4] = {};
  const int ldsb = (tid & 448) * 16;
  for (int kt = 0; kt < 256; kt += 64) {
#pragma unroll
    for (int i = 0; i < 2; ++i)
      gload16(pa[i] + kt + sxa[i], (char*)As + i * 8192 + ldsb);
#pragma unroll
    for (int i = 0; i < 4; ++i)
      gload16(pb[i] + kt + sxb[i], (char*)Bs + i * 8192 + ldsb);
    __syncthreads();
#pragma unroll
    for (int ks = 0; ks < 2; ++ks) {
      const int lc = ks * 4 + (lane >> 4);
      bf16x8 af[4], bfv[4];
#pragma unroll
      for (int mi = 0; mi < 4; ++mi) {
        int row = wr * 64 + mi * 16 + (lane & 15);
        af[mi] = *(const bf16x8*)((const char*)As + row * 128 + ((lc ^ (row & 7)) << 4));
      }
#pragma unroll
      for (int ni = 0; ni < 4; ++ni) {
        int col = wc * 64 + ni * 16 + (lane & 15);
        bfv[ni] = *(const bf16x8*)((const char*)Bs + col * 128 + ((lc ^ (col & 7)) << 4));
      }
#pragma unroll
      for (int mi = 0; mi < 4; ++mi)
#pragma unroll
        for (int ni = 0; ni < 4; ++ni)
          acc[mi][ni] = MFMA16(af[mi], bfv[ni], acc[mi][ni]);
    }
    __syncthreads();
  }
  const bool is_h = (col0 < 256);
#pragma unroll
  for (int mi = 0; mi < 4; ++mi)
#pragma unroll
    for (int ni = 0; ni < 4; ++ni) {
      int c2 = wc * 64 + ni * 16 + (lane & 15);
#pragma unroll
      for (int r = 0; r < 4; ++r) {
        int R = row0 + wr * 64 + mi * 16 + (lane >> 4) * 4 + r;
        float v = acc[mi][ni][r];
        if (is_h) {
          h_bf[(size_t)R * Un + c2] = __float2bfloat16(v);
        } else {
          v += nb[c2];
          v = fmaxf(v, 0.f) * (ng[c2] * BN_SCALE_C) + nbe[c2];
          nupb[(size_t)R * Un + c2] = __float2bfloat16(v);
        }
      }
    }
}

// ------------- fused GRU v2: zero-free B (768,512), grid 1024 1D swizzled
__global__ LB void k_gru_mfma2(const __hip_bfloat16* __restrict__ attb,
                               const __hip_bfloat16* __restrict__ nupb,
                               const __hip_bfloat16* __restrict__ Wt,  // (768,512)
                               const float* __restrict__ bg,           // (768)
                               __hip_bfloat16* __restrict__ nodes_out) {
  __shared__ __align__(16) short As[128 * 64];
  __shared__ __align__(16) short Bs[96 * 64];
  const int tid = threadIdx.x, lane = tid & 63;
  const int w = tid >> 6, wr = w >> 1, wc = w & 1;
  const int bid = blockIdx.x;
  const int wgid = (bid & 7) * 128 + (bid >> 3);   // XCD-chunked
  const int row0 = (wgid >> 3) * 128, c0 = (wgid & 7) * 32;
  const __hip_bfloat16 *paA[4], *paN[4], *pb[3];
  int sxa[4], sxb[3];
#pragma unroll
  for (int i = 0; i < 4; ++i) {
    int c = i * 256 + tid, row = c >> 3, slot = c & 7;
    paA[i] = attb + (size_t)(row0 + row) * Un;
    paN[i] = nupb + (size_t)(row0 + row) * Un;
    sxa[i] = (slot ^ (row & 7)) * 8;
  }
#pragma unroll
  for (int i = 0; i < 3; ++i) {
    int l = i * 256 + tid, j = l >> 3, slot = l & 7;
    int grow = (j < 32) ? (c0 + j) : (j < 64) ? (256 + c0 + (j - 32))
                                              : (512 + c0 + (j - 64));
    pb[i] = Wt + (size_t)grow * 512;
    sxb[i] = (slot ^ (j & 7)) * 8;
  }
  f32x4 acc[4][4] = {};   // [z,r,xh,uh][mi]
  const int ldsb = (tid & 192) * 16;
  for (int kt = 0; kt < 512; kt += 64) {
    const int koff = kt & 255;
    const bool rA = kt < 256;
#pragma unroll
    for (int i = 0; i < 4; ++i) {
      const __hip_bfloat16* s = rA ? paA[i] : paN[i];
      gload16(s + koff + sxa[i], (char*)As + i * 4096 + ldsb);
    }
#pragma unroll
    for (int i = 0; i < 3; ++i)
      gload16(pb[i] + kt + sxb[i], (char*)Bs + i * 4096 + ldsb);
    __syncthreads();
    const int g2 = rA ? 2 : 3;
#pragma unroll
    for (int ks = 0; ks < 2; ++ks) {
      const int lc = ks * 4 + (lane >> 4);
      bf16x8 af[4], bv[3];
      const int jj = wc * 16 + (lane & 15);
      const int jsw = (lc ^ (jj & 7)) << 4;
      bv[0] = *(const bf16x8*)((const char*)Bs + jj * 128 + jsw);
      bv[1] = *(const bf16x8*)((const char*)Bs + (32 + jj) * 128 + jsw);
      bv[2] = *(const bf16x8*)((const char*)Bs + (64 + jj) * 128 + jsw);
#pragma unroll
      for (int mi = 0; mi < 4; ++mi) {
        int row = wr * 64 + mi * 16 + (lane & 15);
        af[mi] = *(const bf16x8*)((const char*)As + row * 128 + ((lc ^ (row & 7)) << 4));
      }
#pragma unroll
      for (int mi = 0; mi < 4; ++mi) {
        acc[0][mi] = MFMA16(af[mi], bv[0], acc[0][mi]);
        acc[1][mi] = MFMA16(af[mi], bv[1], acc[1][mi]);
        acc[g2][mi] = MFMA16(af[mi], bv[2], acc[g2][mi]);
      }
    }
    __syncthreads();
  }
  {
    const int c = c0 + wc * 16 + (lane & 15);
    const float bz = bg[c], br = bg[256 + c], bh = bg[512 + c];
    const unsigned short* nu_u = (const unsigned short*)nupb;
#pragma unroll
    for (int mi = 0; mi < 4; ++mi)
#pragma unroll
      for (int r = 0; r < 4; ++r) {
        int R = row0 + wr * 64 + mi * 16 + (lane >> 4) * 4 + r;
        float z  = sigm(acc[0][mi][r] + bz);
        float rr = sigm(acc[1][mi][r] + br);
        float hh = tanhf(acc[2][mi][r] + bh + rr * acc[3][mi][r]);
        float nu = bf2f(nu_u[(size_t)R * Un + c]);
        nodes_out[(size_t)R * Un + c] = __float2bfloat16(z * nu + (1.f - z) * hh);
      }
  }
}

// ---------------- elog as MFMA mini-GEMM: elog = e_up @ a_slice^T (N=8 pad 16)
// grid 256 x 256 threads (4 waves x 64 rows = 256 rows/block)
__global__ LB void k_elog_mfma(const __hip_bfloat16* __restrict__ e_up, // (B*E,256)
                               const float* __restrict__ a_gat,         // (H,320)
                               float* __restrict__ elog) {              // (B*E,8)
  __shared__ __align__(16) short at[16 * 264];   // a^T bf16, padded stride 264
  const int tid = threadIdx.x, lane = tid & 63, w = tid >> 6;
  for (int l = tid; l < 16 * 264; l += 256) {
    int col = l / 264, k = l % 264;
    float v = (col < 8 && k < 256) ? a_gat[col * 320 + 64 + k] : 0.f;
    __hip_bfloat16 b = __float2bfloat16(v);
    at[l] = *reinterpret_cast<short*>(&b);
  }
  __syncthreads();
  const int rowbase = blockIdx.x * 256 + w * 64;
  const int lrow = lane & 15, lk = (lane >> 4) * 8;
  f32x4 acc[4] = {};
#pragma unroll
  for (int kt = 0; kt < 256; kt += 32) {
    bf16x8 bf = *(const bf16x8*)(at + lrow * 264 + kt + lk);
#pragma unroll
    for (int mi = 0; mi < 4; ++mi) {
      bf16x8 af = *(const bf16x8*)(e_up + (size_t)(rowbase + mi * 16 + lrow) * 256 + kt + lk);
      acc[mi] = MFMA16(af, bf, acc[mi]);
    }
  }
  if (lrow < 8) {
#pragma unroll
    for (int mi = 0; mi < 4; ++mi)
#pragma unroll
      for (int r = 0; r < 4; ++r) {
        int row = rowbase + mi * 16 + (lane >> 4) * 4 + r;
        elog[(size_t)row * 8 + lrow] = acc[mi][r];
      }
  }
}

// ---------------- GAT v3: fused nlog + CSR softmax + LDS-h aggregate (bf16 h)
__global__ LB void k_gat3(const __hip_bfloat16* __restrict__ h,  // (B*N,256) bf16
                          const float* __restrict__ elog,        // (B*E,8)
                          const int* __restrict__ eidx,
                          const float* __restrict__ a_gat,       // (H,320)
                          const float* __restrict__ b_gat,       // (H)
                          __hip_bfloat16* __restrict__ att_bf) { // (B*N,256)
  const int b = blockIdx.x, hg = blockIdx.y;
  __shared__ int s_tgt[En], s_src[En];
  __shared__ float s_at[4][32], s_as[4][32];
  __shared__ float s_lt[Nn][4], s_ls[Nn][4];
  __shared__ float s_L[En][4];
  __shared__ int s_cnt[Nn], s_start[Nn], s_cur[Nn];
  __shared__ short s_ord[En];
  __shared__ float s_bg[4];
  __shared__ __align__(16) unsigned short hl[Nn][136];
  const int tid = threadIdx.x;
  if (tid < 4) s_bg[tid] = b_gat[hg * 4 + tid];
  if (tid < 128) {
    int q = tid >> 5, d = tid & 31;
    s_at[q][d] = a_gat[(hg * 4 + q) * 320 + d];
    s_as[q][d] = a_gat[(hg * 4 + q) * 320 + 32 + d];
  }
  for (int e = tid; e < En; e += 256) {
    s_tgt[e] = eidx[(b * En + e) * 2 + 0];
    s_src[e] = eidx[(b * En + e) * 2 + 1];
  }
  for (int l = tid; l < Nn; l += 256) s_cnt[l] = 0;
  for (int l = tid; l < En * 4; l += 256) {
    int e = l >> 2, q = l & 3;
    s_L[e][q] = elog[(size_t)(b * En + e) * 8 + hg * 4 + q];
  }
  const unsigned short* hu = (const unsigned short*)h;
  for (int l = tid; l < Nn * 16; l += 256) {
    int row = l >> 4, c8 = l & 15;
    u16x8 v = *(const u16x8*)(hu + (size_t)(b * Nn + row) * Un + hg * 128 + c8 * 8);
    *(u16x8*)&hl[row][c8 * 8] = v;
  }
  __syncthreads();
  for (int p = tid; p < Nn * 4; p += 256) {
    int n = p >> 2, q = p & 3;
    const unsigned short* hr = &hl[n][q * 32];
    float lt = 0.f, ls = 0.f;
#pragma unroll
    for (int c8 = 0; c8 < 4; ++c8) {
      u16x8 v = *(const u16x8*)(hr + c8 * 8);
#pragma unroll
      for (int j = 0; j < 8; ++j) {
        float f = bf2f(v[j]);
        int d = c8 * 8 + j;
        lt += f * s_at[q][d];
        ls += f * s_as[q][d];
      }
    }
    s_lt[n][q] = lt; s_ls[n][q] = ls;
  }
  for (int e = tid; e < En; e += 256) atomicAdd(&s_cnt[s_tgt[e]], 1);
  __syncthreads();
  if (tid == 0) {
    int acc = 0;
    for (int n = 0; n < Nn; ++n) { s_start[n] = acc; s_cur[n] = acc; acc += s_cnt[n]; }
  }
  __syncthreads();
  for (int e = tid; e < En; e += 256) {
    int pos = atomicAdd(&s_cur[s_tgt[e]], 1);
    s_ord[pos] = (short)e;
  }
  for (int l = tid; l < En * 4; l += 256) {
    int e = l >> 2, q = l & 3;
    float v = s_lt[s_tgt[e]][q] + s_ls[s_src[e]][q] + s_L[e][q] + s_bg[q];
    v = (v > 0.f) ? v : 0.2f * v;
    s_L[e][q] = v;
  }
  __syncthreads();
  for (int p = tid; p < Nn * 4; p += 256) {
    const int n = p >> 2, q = p & 3;
    const int st = s_start[n], cn = s_cnt[n];
    float m = -1e9f;
    for (int i = 0; i < cn; ++i) m = fmaxf(m, s_L[s_ord[st + i]][q]);
    float den = 1e-9f;
    for (int i = 0; i < cn; ++i) {
      const int e = s_ord[st + i];
      float ex = expf(s_L[e][q] - m);
      s_L[e][q] = ex;
      den += ex;
    }
    const float inv = 1.f / den;
    float acc[32] = {};
    for (int i = 0; i < cn; ++i) {
      const int e = s_ord[st + i];
      const float wgt = s_L[e][q] * inv;
      const unsigned short* hs = &hl[s_src[e]][q * 32];
#pragma unroll
      for (int c8 = 0; c8 < 4; ++c8) {
        u16x8 v = *(const u16x8*)(hs + c8 * 8);
#pragma unroll
        for (int j = 0; j < 8; ++j) acc[c8 * 8 + j] += wgt * bf2f(v[j]);
      }
    }
    __hip_bfloat16* ob = att_bf + (size_t)(b * Nn + n) * Un + (hg * 4 + q) * DHn;
#pragma unroll
    for (int d = 0; d < 32; ++d) ob[d] = __float2bfloat16(fmaxf(acc[d], 0.f));
  }
}

// -------------------------------------------------- mean-pool + MLP head
__global__ LB void k_pool(const __hip_bfloat16* __restrict__ nodes,
                          const float* __restrict__ Wp1, const float* __restrict__ bp1,
                          const float* __restrict__ Wp2, const float* __restrict__ bp2,
                          float* __restrict__ out) {
  const int b = blockIdx.x, tid = threadIdx.x;
  __shared__ float e0[256], e1[256];
  float s = 0.f;
  for (int n = 0; n < Nn; ++n) s += __bfloat162float(nodes[(size_t)(b * Nn + n) * Un + tid]);
  e0[tid] = s * (1.f / Nn);
  __syncthreads();
  float a1 = bp1[tid];
  for (int k = 0; k < 256; ++k) a1 += e0[k] * Wp1[k * 256 + tid];
  e1[tid] = fmaxf(a1, 0.f);
  __syncthreads();
  if (tid < 128) {
    float a2 = bp2[tid];
    for (int k = 0; k < 256; ++k) a2 += e1[k] * Wp2[k * 128 + tid];
    a2 = fmaxf(a2, 0.f);
    out[b * 128 + tid] = a2;
    out[Bn * 128 + b * 256 + tid] = a2;
    out[Bn * 128 + b * 256 + 128 + tid] = a2;
  }
}

extern "C" void kernel_launch(void* const* d_in, const int* in_sizes, int n_in,
                              void* d_out, int out_size, void* d_ws, size_t ws_size,
                              hipStream_t stream) {
  const float* node_attr = (const float*)d_in[0];
  const float* edge_attr = (const float*)d_in[1];
  const int*   eidx      = (const int*)d_in[2];
  const float* W_edge    = (const float*)d_in[3];
  const float* b_edge    = (const float*)d_in[4];
  const float* gamma_e   = (const float*)d_in[5];
  const float* beta_e    = (const float*)d_in[6];
  const float* W_node    = (const float*)d_in[7];
  const float* b_node    = (const float*)d_in[8];
  const float* gamma_n   = (const float*)d_in[9];
  const float* beta_n    = (const float*)d_in[10];
  const float* W_gat     = (const float*)d_in[11];
  const float* a_gat     = (const float*)d_in[12];
  const float* b_gat     = (const float*)d_in[13];
  const float* W_gru     = (const float*)d_in[14];
  const float* U_gru     = (const float*)d_in[15];
  const float* b_gru     = (const float*)d_in[16];
  const float* W_p1      = (const float*)d_in[17];
  const float* b_p1      = (const float*)d_in[18];
  const float* W_p2      = (const float*)d_in[19];
  const float* b_p2      = (const float*)d_in[20];

  char* p = (char*)d_ws;
  auto alloc = [&](size_t bytes) { char* q = p; p += (bytes + 255) & ~255ull; return q; };
  const size_t NODE_EL = (size_t)Bn * Nn * Un;   // 4,194,304
  const size_t EDGE_EL = (size_t)Bn * En * Un;   // 16,777,216
  __hip_bfloat16* nodes_bf = (__hip_bfloat16*)alloc(NODE_EL * 2);
  __hip_bfloat16* h_bf   = (__hip_bfloat16*)alloc(NODE_EL * 2);
  __hip_bfloat16* nup_bf = (__hip_bfloat16*)alloc(NODE_EL * 2);
  __hip_bfloat16* att_bf = (__hip_bfloat16*)alloc(NODE_EL * 2);
  float* elog   = (float*)alloc((size_t)Bn * En * 8 * 4);
  __hip_bfloat16* edges_a = (__hip_bfloat16*)alloc(EDGE_EL * 2);
  __hip_bfloat16* edges_b = (__hip_bfloat16*)alloc(EDGE_EL * 2);
  __hip_bfloat16* Wt_e   = (__hip_bfloat16*)alloc((size_t)Dn * 256 * 768 * 2);
  __hip_bfloat16* Wt_hn  = (__hip_bfloat16*)alloc((size_t)Dn * 512 * 256 * 2);
  __hip_bfloat16* Wt_gru = (__hip_bfloat16*)alloc((size_t)Dn * 768 * 512 * 2);

  k_f2bf<<<(int)(EDGE_EL / 1024), 256, 0, stream>>>(edge_attr, edges_a, (int)EDGE_EL);
  k_f2bf<<<(int)(NODE_EL / 1024), 256, 0, stream>>>(node_attr, nodes_bf, (int)NODE_EL);
  k_prep_edge<<<(Dn * 256 * 768) / 256, 256, 0, stream>>>(W_edge, Wt_e);
  k_prep_hn<<<(Dn * 512 * 256) / 256, 256, 0, stream>>>(W_gat, W_node, Wt_hn);
  k_prep_gru2<<<(Dn * 768 * 512) / 256, 256, 0, stream>>>(W_gru, U_gru, Wt_gru);

  __hip_bfloat16* ein = edges_a;
  __hip_bfloat16* eout = edges_b;
  for (int d = 0; d < Dn; ++d) {
    k_edge_mfma<<<512, 512, 0, stream>>>(
        nodes_bf, ein, eidx, Wt_e + (size_t)d * 256 * 768, b_edge + d * Un,
        gamma_e + d * Un, beta_e + d * Un, eout);
    k_hn_mfma<<<256, 512, 0, stream>>>(
        nodes_bf, Wt_hn + (size_t)d * 512 * 256, b_node + d * Un,
        gamma_n + d * Un, beta_n + d * Un, h_bf, nup_bf);
    k_elog_mfma<<<(Bn * En) / 256, 256, 0, stream>>>(
        eout, a_gat + (size_t)d * Hn * 320, elog);
    k_gat3<<<dim3(Bn, 2), 256, 0, stream>>>(
        h_bf, elog, eidx, a_gat + (size_t)d * Hn * 320, b_gat + d * Hn, att_bf);
    k_gru_mfma2<<<1024, 256, 0, stream>>>(
        att_bf, nup_bf, Wt_gru + (size_t)d * 768 * 512, b_gru + d * 3 * Un,
        nodes_bf);
    __hip_bfloat16* t = ein; ein = eout; eout = t;
  }
  k_pool<<<Bn, 256, 0, stream>>>(nodes_bf, W_p1, b_p1, W_p2, b_p2, (float*)d_out);
}

// Round 12
// 365.530 us; speedup vs baseline: 1.2174x; 1.0106x over previous
//
#include <hip/hip_runtime.h>
#include <hip/hip_bf16.h>

constexpr int Dn  = 3;
constexpr int Un  = 256;
constexpr int Hn  = 8;
constexpr int DHn = 32;
constexpr int Bn  = 128;
constexpr int Nn  = 128;
constexpr int En  = 512;
constexpr float BN_SCALE_C = 0.9995003746877732f; // 1/sqrt(1.001)

#define LB __launch_bounds__(256)
#define LB8 __launch_bounds__(512)

typedef short bf16x8 __attribute__((ext_vector_type(8)));
typedef unsigned short u16x8 __attribute__((ext_vector_type(8)));
typedef float f32x4 __attribute__((ext_vector_type(4)));
#define MFMA16(a, b, c) __builtin_amdgcn_mfma_f32_16x16x32_bf16(a, b, c, 0, 0, 0)

__device__ __forceinline__ void gload16(const void* g, void* l) {
  __builtin_amdgcn_global_load_lds(
      (const __attribute__((address_space(1))) void*)g,
      (__attribute__((address_space(3))) void*)l, 16, 0, 0);
}
__device__ __forceinline__ float sigm(float x) { return 1.f / (1.f + expf(-x)); }
__device__ __forceinline__ float bf2f(unsigned short u) {
  return __uint_as_float((unsigned)u << 16);
}

// ---------------------------------------------------------------- f32 -> bf16
__global__ LB void k_f2bf(const float* __restrict__ in,
                          __hip_bfloat16* __restrict__ out, int n) {
  int i = (blockIdx.x * 256 + threadIdx.x) * 4;
  if (i + 3 < n) {
    float4 v = *reinterpret_cast<const float4*>(in + i);
    out[i + 0] = __float2bfloat16(v.x);
    out[i + 1] = __float2bfloat16(v.y);
    out[i + 2] = __float2bfloat16(v.z);
    out[i + 3] = __float2bfloat16(v.w);
  }
}

// --------------------------- weight prep: transpose + bf16 (B^T layouts)
__global__ LB void k_prep_edge(const float* __restrict__ W,  // (D,768,256)
                               __hip_bfloat16* __restrict__ Wt) { // (D,256,768)
  int idx = blockIdx.x * 256 + threadIdx.x;
  int d = idx / (Un * 3 * Un);
  int rem = idx % (Un * 3 * Un);
  int n = rem / (3 * Un);
  int k = rem % (3 * Un);
  Wt[idx] = __float2bfloat16(W[(size_t)d * 3 * Un * Un + (size_t)k * Un + n]);
}

__global__ LB void k_prep_hn(const float* __restrict__ Wg,   // (D,256,256)
                             const float* __restrict__ Wn,   // (D,256,256)
                             __hip_bfloat16* __restrict__ Wt) { // (D,512,256)
  int idx = blockIdx.x * 256 + threadIdx.x;
  int d = idx / (512 * 256);
  int rem = idx % (512 * 256);
  int n = rem / 256;
  int k = rem % 256;
  float v = (n < 256) ? Wg[(size_t)d * 65536 + k * 256 + n]
                      : Wn[(size_t)d * 65536 + k * 256 + (n - 256)];
  Wt[idx] = __float2bfloat16(v);
}

// B2[j2][k], j2 in [0,768): z (full K), r (full K), xh/uh time-shared.
__global__ LB void k_prep_gru2(const float* __restrict__ W,   // (D,256,768)
                               const float* __restrict__ U,   // (D,256,768)
                               __hip_bfloat16* __restrict__ Wt) { // (D,768,512)
  int idx = blockIdx.x * 256 + threadIdx.x;
  int d = idx / (768 * 512);
  int rem = idx % (768 * 512);
  int j2 = rem >> 9;
  int k = rem & 511;
  const size_t wb = (size_t)d * 196608;
  float v = (k < 256) ? W[wb + k * 768 + j2] : U[wb + (k - 256) * 768 + j2];
  Wt[idx] = __float2bfloat16(v);
}

// ---------------- MFMA edge GEMM (M=65536,K=768,N=256), 8 waves, 128x256 tile
__global__ LB8 void k_edge_mfma(const __hip_bfloat16* __restrict__ nodes,
                                const __hip_bfloat16* __restrict__ edges,
                                const int* __restrict__ eidx,
                                const __hip_bfloat16* __restrict__ Wt, // (256,768)
                                const float* __restrict__ bias,
                                const float* __restrict__ gamma,
                                const float* __restrict__ beta,
                                __hip_bfloat16* __restrict__ e_up) {
  __shared__ __align__(16) short As[128 * 64];   // 16 KB
  __shared__ __align__(16) short Bs[256 * 64];   // 32 KB
  const int tid = threadIdx.x, lane = tid & 63;
  const int w = tid >> 6, wr = w >> 2, wc = w & 3;   // 2 x 4 waves
  const int bid = blockIdx.x;
  const int wgid = (bid & 7) * 64 + (bid >> 3);      // XCD-chunked
  const int row0 = wgid * 128;
  const __hip_bfloat16 *pa0[2], *pa1[2], *pa2[2], *pb[4];
  int sxa[2], sxb[4];
#pragma unroll
  for (int i = 0; i < 2; ++i) {
    int c = i * 512 + tid, row = c >> 3, slot = c & 7;
    int R = row0 + row, b = R >> 9, e = R & 511;
    int tt = eidx[(b * En + e) * 2 + 0];
    int ss = eidx[(b * En + e) * 2 + 1];
    pa0[i] = nodes + (size_t)(b * Nn + ss) * Un;
    pa1[i] = nodes + (size_t)(b * Nn + tt) * Un;
    pa2[i] = edges + (size_t)(b * En + e) * Un;
    sxa[i] = (slot ^ (row & 7)) * 8;
  }
#pragma unroll
  for (int i = 0; i < 4; ++i) {
    int c = i * 512 + tid, j = c >> 3, slot = c & 7;
    pb[i] = Wt + (size_t)j * 768;
    sxb[i] = (slot ^ (j & 7)) * 8;
  }
  f32x4 acc[4][4] = {};
  const int ldsb = (tid & 448) * 16;   // 64-lane-group uniform base
  for (int kt = 0; kt < 768; kt += 64) {
    const int region = kt >> 8, koff = kt & 255;
#pragma unroll
    for (int i = 0; i < 2; ++i) {
      const __hip_bfloat16* s = (region == 0) ? pa0[i] : (region == 1 ? pa1[i] : pa2[i]);
      gload16(s + koff + sxa[i], (char*)As + i * 8192 + ldsb);
    }
#pragma unroll
    for (int i = 0; i < 4; ++i)
      gload16(pb[i] + kt + sxb[i], (char*)Bs + i * 8192 + ldsb);
    __syncthreads();
#pragma unroll
    for (int ks = 0; ks < 2; ++ks) {
      const int lc = ks * 4 + (lane >> 4);
      bf16x8 af[4], bfv[4];
#pragma unroll
      for (int mi = 0; mi < 4; ++mi) {
        int row = wr * 64 + mi * 16 + (lane & 15);
        af[mi] = *(const bf16x8*)((const char*)As + row * 128 + ((lc ^ (row & 7)) << 4));
      }
#pragma unroll
      for (int ni = 0; ni < 4; ++ni) {
        int col = wc * 64 + ni * 16 + (lane & 15);
        bfv[ni] = *(const bf16x8*)((const char*)Bs + col * 128 + ((lc ^ (col & 7)) << 4));
      }
#pragma unroll
      for (int mi = 0; mi < 4; ++mi)
#pragma unroll
        for (int ni = 0; ni < 4; ++ni)
          acc[mi][ni] = MFMA16(af[mi], bfv[ni], acc[mi][ni]);
    }
    __syncthreads();
  }
#pragma unroll
  for (int mi = 0; mi < 4; ++mi)
#pragma unroll
    for (int ni = 0; ni < 4; ++ni) {
      int C = wc * 64 + ni * 16 + (lane & 15);
      float gs = gamma[C] * BN_SCALE_C, bt = beta[C], bi = bias[C];
#pragma unroll
      for (int r = 0; r < 4; ++r) {
        int R = row0 + wr * 64 + mi * 16 + (lane >> 4) * 4 + r;
        float v = acc[mi][ni][r] + bi;
        v = fmaxf(v, 0.f) * gs + bt;
        e_up[(size_t)R * Un + C] = __float2bfloat16(v);
      }
    }
}

// ------------- MFMA h/n_up GEMM (M=16384,K=256,N=512), 8 waves, 128x256 tile
__global__ LB8 void k_hn_mfma(const __hip_bfloat16* __restrict__ A,
                              const __hip_bfloat16* __restrict__ Wt, // (512,256)
                              const float* __restrict__ nb,
                              const float* __restrict__ ng,
                              const float* __restrict__ nbe,
                              __hip_bfloat16* __restrict__ h_bf,
                              __hip_bfloat16* __restrict__ nupb) {
  __shared__ __align__(16) short As[128 * 64];
  __shared__ __align__(16) short Bs[256 * 64];
  const int tid = threadIdx.x, lane = tid & 63;
  const int w = tid >> 6, wr = w >> 2, wc = w & 3;
  const int bid = blockIdx.x;
  const int wgid = (bid & 7) * 32 + (bid >> 3);      // XCD-chunked
  const int row0 = (wgid >> 1) * 128, col0 = (wgid & 1) * 256;
  const __hip_bfloat16 *pa[2], *pb[4];
  int sxa[2], sxb[4];
#pragma unroll
  for (int i = 0; i < 2; ++i) {
    int c = i * 512 + tid, row = c >> 3, slot = c & 7;
    pa[i] = A + (size_t)(row0 + row) * Un;
    sxa[i] = (slot ^ (row & 7)) * 8;
  }
#pragma unroll
  for (int i = 0; i < 4; ++i) {
    int c = i * 512 + tid, j = c >> 3, slot = c & 7;
    pb[i] = Wt + (size_t)(col0 + j) * Un;
    sxb[i] = (slot ^ (j & 7)) * 8;
  }
  f32x4 acc[4][4] = {};
  const int ldsb = (tid & 448) * 16;
  for (int kt = 0; kt < 256; kt += 64) {
#pragma unroll
    for (int i = 0; i < 2; ++i)
      gload16(pa[i] + kt + sxa[i], (char*)As + i * 8192 + ldsb);
#pragma unroll
    for (int i = 0; i < 4; ++i)
      gload16(pb[i] + kt + sxb[i], (char*)Bs + i * 8192 + ldsb);
    __syncthreads();
#pragma unroll
    for (int ks = 0; ks < 2; ++ks) {
      const int lc = ks * 4 + (lane >> 4);
      bf16x8 af[4], bfv[4];
#pragma unroll
      for (int mi = 0; mi < 4; ++mi) {
        int row = wr * 64 + mi * 16 + (lane & 15);
        af[mi] = *(const bf16x8*)((const char*)As + row * 128 + ((lc ^ (row & 7)) << 4));
      }
#pragma unroll
      for (int ni = 0; ni < 4; ++ni) {
        int col = wc * 64 + ni * 16 + (lane & 15);
        bfv[ni] = *(const bf16x8*)((const char*)Bs + col * 128 + ((lc ^ (col & 7)) << 4));
      }
#pragma unroll
      for (int mi = 0; mi < 4; ++mi)
#pragma unroll
        for (int ni = 0; ni < 4; ++ni)
          acc[mi][ni] = MFMA16(af[mi], bfv[ni], acc[mi][ni]);
    }
    __syncthreads();
  }
  const bool is_h = (col0 < 256);
#pragma unroll
  for (int mi = 0; mi < 4; ++mi)
#pragma unroll
    for (int ni = 0; ni < 4; ++ni) {
      int c2 = wc * 64 + ni * 16 + (lane & 15);
#pragma unroll
      for (int r = 0; r < 4; ++r) {
        int R = row0 + wr * 64 + mi * 16 + (lane >> 4) * 4 + r;
        float v = acc[mi][ni][r];
        if (is_h) {
          h_bf[(size_t)R * Un + c2] = __float2bfloat16(v);
        } else {
          v += nb[c2];
          v = fmaxf(v, 0.f) * (ng[c2] * BN_SCALE_C) + nbe[c2];
          nupb[(size_t)R * Un + c2] = __float2bfloat16(v);
        }
      }
    }
}

// ------------- fused GRU v3: zero-free B (768,512), 8 waves, 128x64 tile
// grid 512 x 512 threads; sections z / r / xh-uh time-shared.
__global__ LB8 void k_gru_mfma3(const __hip_bfloat16* __restrict__ attb,
                                const __hip_bfloat16* __restrict__ nupb,
                                const __hip_bfloat16* __restrict__ Wt,  // (768,512)
                                const float* __restrict__ bg,           // (768)
                                __hip_bfloat16* __restrict__ nodes_out) {
  __shared__ __align__(16) short As[128 * 64];   // 16 KB
  __shared__ __align__(16) short Bs[192 * 64];   // 24 KB
  const int tid = threadIdx.x, lane = tid & 63;
  const int w = tid >> 6, wr = w >> 2, wc = w & 3;   // 2 x 4 waves
  const int bid = blockIdx.x;
  const int wgid = (bid & 7) * 64 + (bid >> 3);      // XCD-chunked (512 blocks)
  const int row0 = (wgid >> 2) * 128, c0 = (wgid & 3) * 64;
  const __hip_bfloat16 *paA[2], *paN[2], *pb[3];
  int sxa[2], sxb[3];
#pragma unroll
  for (int i = 0; i < 2; ++i) {
    int c = i * 512 + tid, row = c >> 3, slot = c & 7;
    paA[i] = attb + (size_t)(row0 + row) * Un;
    paN[i] = nupb + (size_t)(row0 + row) * Un;
    sxa[i] = (slot ^ (row & 7)) * 8;
  }
#pragma unroll
  for (int i = 0; i < 3; ++i) {
    int l = i * 512 + tid, j = l >> 3, slot = l & 7;
    int sec = j >> 6, jj = j & 63;
    pb[i] = Wt + (size_t)(sec * 256 + c0 + jj) * 512;
    sxb[i] = (slot ^ (j & 7)) * 8;
  }
  f32x4 acc[4][4] = {};   // [z,r,xh,uh][mi]
  const int ldsb = (tid & 448) * 16;
  for (int kt = 0; kt < 512; kt += 64) {
    const int koff = kt & 255;
    const bool rA = kt < 256;
#pragma unroll
    for (int i = 0; i < 2; ++i) {
      const __hip_bfloat16* s = rA ? paA[i] : paN[i];
      gload16(s + koff + sxa[i], (char*)As + i * 8192 + ldsb);
    }
#pragma unroll
    for (int i = 0; i < 3; ++i)
      gload16(pb[i] + kt + sxb[i], (char*)Bs + i * 8192 + ldsb);
    __syncthreads();
    const int g2 = rA ? 2 : 3;
#pragma unroll
    for (int ks = 0; ks < 2; ++ks) {
      const int lc = ks * 4 + (lane >> 4);
      bf16x8 af[4], bv[3];
#pragma unroll
      for (int s = 0; s < 3; ++s) {
        int j = s * 64 + wc * 16 + (lane & 15);
        bv[s] = *(const bf16x8*)((const char*)Bs + j * 128 + ((lc ^ (j & 7)) << 4));
      }
#pragma unroll
      for (int mi = 0; mi < 4; ++mi) {
        int row = wr * 64 + mi * 16 + (lane & 15);
        af[mi] = *(const bf16x8*)((const char*)As + row * 128 + ((lc ^ (row & 7)) << 4));
      }
#pragma unroll
      for (int mi = 0; mi < 4; ++mi) {
        acc[0][mi] = MFMA16(af[mi], bv[0], acc[0][mi]);
        acc[1][mi] = MFMA16(af[mi], bv[1], acc[1][mi]);
        acc[g2][mi] = MFMA16(af[mi], bv[2], acc[g2][mi]);
      }
    }
    __syncthreads();
  }
  {
    const int c = c0 + wc * 16 + (lane & 15);
    const float bz = bg[c], br = bg[256 + c], bh = bg[512 + c];
    const unsigned short* nu_u = (const unsigned short*)nupb;
#pragma unroll
    for (int mi = 0; mi < 4; ++mi)
#pragma unroll
      for (int r = 0; r < 4; ++r) {
        int R = row0 + wr * 64 + mi * 16 + (lane >> 4) * 4 + r;
        float z  = sigm(acc[0][mi][r] + bz);
        float rr = sigm(acc[1][mi][r] + br);
        float hh = tanhf(acc[2][mi][r] + bh + rr * acc[3][mi][r]);
        float nu = bf2f(nu_u[(size_t)R * Un + c]);
        nodes_out[(size_t)R * Un + c] = __float2bfloat16(z * nu + (1.f - z) * hh);
      }
  }
}

// ---------------- elog as MFMA mini-GEMM: elog = e_up @ a_slice^T (N=8 pad 16)
__global__ LB void k_elog_mfma(const __hip_bfloat16* __restrict__ e_up, // (B*E,256)
                               const float* __restrict__ a_gat,         // (H,320)
                               float* __restrict__ elog) {              // (B*E,8)
  __shared__ __align__(16) short at[16 * 264];   // a^T bf16, padded stride 264
  const int tid = threadIdx.x, lane = tid & 63, w = tid >> 6;
  for (int l = tid; l < 16 * 264; l += 256) {
    int col = l / 264, k = l % 264;
    float v = (col < 8 && k < 256) ? a_gat[col * 320 + 64 + k] : 0.f;
    __hip_bfloat16 b = __float2bfloat16(v);
    at[l] = *reinterpret_cast<short*>(&b);
  }
  __syncthreads();
  const int rowbase = blockIdx.x * 256 + w * 64;
  const int lrow = lane & 15, lk = (lane >> 4) * 8;
  f32x4 acc[4] = {};
#pragma unroll
  for (int kt = 0; kt < 256; kt += 32) {
    bf16x8 bf = *(const bf16x8*)(at + lrow * 264 + kt + lk);
#pragma unroll
    for (int mi = 0; mi < 4; ++mi) {
      bf16x8 af = *(const bf16x8*)(e_up + (size_t)(rowbase + mi * 16 + lrow) * 256 + kt + lk);
      acc[mi] = MFMA16(af, bf, acc[mi]);
    }
  }
  if (lrow < 8) {
#pragma unroll
    for (int mi = 0; mi < 4; ++mi)
#pragma unroll
      for (int r = 0; r < 4; ++r) {
        int row = rowbase + mi * 16 + (lane >> 4) * 4 + r;
        elog[(size_t)row * 8 + lrow] = acc[mi][r];
      }
  }
}

// ---------------- GAT v4: per-(batch,head) block; CSR softmax + LDS-h aggregate
// grid (Bn, Hn); LDS ~20 KB -> high occupancy; all 256 threads active per phase.
__global__ LB void k_gat4(const __hip_bfloat16* __restrict__ h,  // (B*N,256) bf16
                          const float* __restrict__ elog,        // (B*E,8)
                          const int* __restrict__ eidx,
                          const float* __restrict__ a_gat,       // (H,320)
                          const float* __restrict__ b_gat,       // (H)
                          __hip_bfloat16* __restrict__ att_bf) { // (B*N,256)
  const int b = blockIdx.x, q = blockIdx.y;
  __shared__ int s_tgt[En], s_src[En];
  __shared__ float s_at[32], s_as[32];
  __shared__ float s_lt[Nn], s_ls[Nn];
  __shared__ float s_L[En];
  __shared__ int s_cnt[Nn], s_start[Nn], s_cur[Nn];
  __shared__ short s_ord[En];
  __shared__ __align__(16) unsigned short hl[Nn][40];  // 32 cols + pad
  const int tid = threadIdx.x;
  const float bgq = b_gat[q];
  if (tid < 32) {
    s_at[tid] = a_gat[q * 320 + tid];
    s_as[tid] = a_gat[q * 320 + 32 + tid];
  }
  for (int e = tid; e < En; e += 256) {
    s_tgt[e] = eidx[(b * En + e) * 2 + 0];
    s_src[e] = eidx[(b * En + e) * 2 + 1];
  }
  if (tid < Nn) s_cnt[tid] = 0;
  for (int e = tid; e < En; e += 256)
    s_L[e] = elog[(size_t)(b * En + e) * 8 + q];
  const unsigned short* hu = (const unsigned short*)h;
  for (int l = tid; l < Nn * 4; l += 256) {
    int row = l >> 2, c8 = l & 3;
    u16x8 v = *(const u16x8*)(hu + (size_t)(b * Nn + row) * Un + q * DHn + c8 * 8);
    *(u16x8*)&hl[row][c8 * 8] = v;
  }
  __syncthreads();
  if (tid < Nn) {
    const unsigned short* hr = hl[tid];
    float lt = 0.f, ls = 0.f;
#pragma unroll
    for (int c8 = 0; c8 < 4; ++c8) {
      u16x8 v = *(const u16x8*)(hr + c8 * 8);
#pragma unroll
      for (int j = 0; j < 8; ++j) {
        float f = bf2f(v[j]);
        int d = c8 * 8 + j;
        lt += f * s_at[d];
        ls += f * s_as[d];
      }
    }
    s_lt[tid] = lt; s_ls[tid] = ls;
  }
  for (int e = tid; e < En; e += 256) atomicAdd(&s_cnt[s_tgt[e]], 1);
  __syncthreads();
  if (tid == 0) {
    int acc = 0;
    for (int n = 0; n < Nn; ++n) { s_start[n] = acc; s_cur[n] = acc; acc += s_cnt[n]; }
  }
  __syncthreads();
  for (int e = tid; e < En; e += 256) {
    int pos = atomicAdd(&s_cur[s_tgt[e]], 1);
    s_ord[pos] = (short)e;
  }
  for (int e = tid; e < En; e += 256) {
    float v = s_lt[s_tgt[e]] + s_ls[s_src[e]] + s_L[e] + bgq;
    v = (v > 0.f) ? v : 0.2f * v;   // leaky_relu(0.2)
    s_L[e] = v;
  }
  __syncthreads();
  // per node: max -> exp(cache) -> den ; store inv-den in s_lt (logits consumed)
  if (tid < Nn) {
    const int st = s_start[tid], cn = s_cnt[tid];
    float m = -1e9f;
    for (int i = 0; i < cn; ++i) m = fmaxf(m, s_L[s_ord[st + i]]);
    float den = 1e-9f;
    for (int i = 0; i < cn; ++i) {
      const int e = s_ord[st + i];
      float ex = expf(s_L[e] - m);
      s_L[e] = ex;
      den += ex;
    }
    s_lt[tid] = 1.f / den;
  }
  __syncthreads();
  // aggregate: 2 threads per node (16 dims each)
  {
    const int n = tid >> 1, half = tid & 1;
    const int st = s_start[n], cn = s_cnt[n];
    const float inv = s_lt[n];
    float acc[16] = {};
    for (int i = 0; i < cn; ++i) {
      const int e = s_ord[st + i];
      const float wgt = s_L[e] * inv;
      const unsigned short* hs = &hl[s_src[e]][half * 16];
#pragma unroll
      for (int c8 = 0; c8 < 2; ++c8) {
        u16x8 v = *(const u16x8*)(hs + c8 * 8);
#pragma unroll
        for (int j = 0; j < 8; ++j) acc[c8 * 8 + j] += wgt * bf2f(v[j]);
      }
    }
    __hip_bfloat16* ob = att_bf + (size_t)(b * Nn + n) * Un + q * DHn + half * 16;
#pragma unroll
    for (int d = 0; d < 16; ++d) ob[d] = __float2bfloat16(fmaxf(acc[d], 0.f));
  }
}

// -------------------------------------------------- mean-pool + MLP head
__global__ LB void k_pool(const __hip_bfloat16* __restrict__ nodes,
                          const float* __restrict__ Wp1, const float* __restrict__ bp1,
                          const float* __restrict__ Wp2, const float* __restrict__ bp2,
                          float* __restrict__ out) {
  const int b = blockIdx.x, tid = threadIdx.x;
  __shared__ float e0[256], e1[256];
  float s = 0.f;
  for (int n = 0; n < Nn; ++n) s += __bfloat162float(nodes[(size_t)(b * Nn + n) * Un + tid]);
  e0[tid] = s * (1.f / Nn);
  __syncthreads();
  float a1 = bp1[tid];
  for (int k = 0; k < 256; ++k) a1 += e0[k] * Wp1[k * 256 + tid];
  e1[tid] = fmaxf(a1, 0.f);
  __syncthreads();
  if (tid < 128) {
    float a2 = bp2[tid];
    for (int k = 0; k < 256; ++k) a2 += e1[k] * Wp2[k * 128 + tid];
    a2 = fmaxf(a2, 0.f);
    out[b * 128 + tid] = a2;
    out[Bn * 128 + b * 256 + tid] = a2;
    out[Bn * 128 + b * 256 + 128 + tid] = a2;
  }
}

extern "C" void kernel_launch(void* const* d_in, const int* in_sizes, int n_in,
                              void* d_out, int out_size, void* d_ws, size_t ws_size,
                              hipStream_t stream) {
  const float* node_attr = (const float*)d_in[0];
  const float* edge_attr = (const float*)d_in[1];
  const int*   eidx      = (const int*)d_in[2];
  const float* W_edge    = (const float*)d_in[3];
  const float* b_edge    = (const float*)d_in[4];
  const float* gamma_e   = (const float*)d_in[5];
  const float* beta_e    = (const float*)d_in[6];
  const float* W_node    = (const float*)d_in[7];
  const float* b_node    = (const float*)d_in[8];
  const float* gamma_n   = (const float*)d_in[9];
  const float* beta_n    = (const float*)d_in[10];
  const float* W_gat     = (const float*)d_in[11];
  const float* a_gat     = (const float*)d_in[12];
  const float* b_gat     = (const float*)d_in[13];
  const float* W_gru     = (const float*)d_in[14];
  const float* U_gru     = (const float*)d_in[15];
  const float* b_gru     = (const float*)d_in[16];
  const float* W_p1      = (const float*)d_in[17];
  const float* b_p1      = (const float*)d_in[18];
  const float* W_p2      = (const float*)d_in[19];
  const float* b_p2      = (const float*)d_in[20];

  char* p = (char*)d_ws;
  auto alloc = [&](size_t bytes) { char* q = p; p += (bytes + 255) & ~255ull; return q; };
  const size_t NODE_EL = (size_t)Bn * Nn * Un;   // 4,194,304
  const size_t EDGE_EL = (size_t)Bn * En * Un;   // 16,777,216
  __hip_bfloat16* nodes_bf = (__hip_bfloat16*)alloc(NODE_EL * 2);
  __hip_bfloat16* h_bf   = (__hip_bfloat16*)alloc(NODE_EL * 2);
  __hip_bfloat16* nup_bf = (__hip_bfloat16*)alloc(NODE_EL * 2);
  __hip_bfloat16* att_bf = (__hip_bfloat16*)alloc(NODE_EL * 2);
  float* elog   = (float*)alloc((size_t)Bn * En * 8 * 4);
  __hip_bfloat16* edges_a = (__hip_bfloat16*)alloc(EDGE_EL * 2);
  __hip_bfloat16* edges_b = (__hip_bfloat16*)alloc(EDGE_EL * 2);
  __hip_bfloat16* Wt_e   = (__hip_bfloat16*)alloc((size_t)Dn * 256 * 768 * 2);
  __hip_bfloat16* Wt_hn  = (__hip_bfloat16*)alloc((size_t)Dn * 512 * 256 * 2);
  __hip_bfloat16* Wt_gru = (__hip_bfloat16*)alloc((size_t)Dn * 768 * 512 * 2);

  k_f2bf<<<(int)(EDGE_EL / 1024), 256, 0, stream>>>(edge_attr, edges_a, (int)EDGE_EL);
  k_f2bf<<<(int)(NODE_EL / 1024), 256, 0, stream>>>(node_attr, nodes_bf, (int)NODE_EL);
  k_prep_edge<<<(Dn * 256 * 768) / 256, 256, 0, stream>>>(W_edge, Wt_e);
  k_prep_hn<<<(Dn * 512 * 256) / 256, 256, 0, stream>>>(W_gat, W_node, Wt_hn);
  k_prep_gru2<<<(Dn * 768 * 512) / 256, 256, 0, stream>>>(W_gru, U_gru, Wt_gru);

  __hip_bfloat16* ein = edges_a;
  __hip_bfloat16* eout = edges_b;
  for (int d = 0; d < Dn; ++d) {
    k_edge_mfma<<<512, 512, 0, stream>>>(
        nodes_bf, ein, eidx, Wt_e + (size_t)d * 256 * 768, b_edge + d * Un,
        gamma_e + d * Un, beta_e + d * Un, eout);
    k_hn_mfma<<<256, 512, 0, stream>>>(
        nodes_bf, Wt_hn + (size_t)d * 512 * 256, b_node + d * Un,
        gamma_n + d * Un, beta_n + d * Un, h_bf, nup_bf);
    k_elog_mfma<<<(Bn * En) / 256, 256, 0, stream>>>(
        eout, a_gat + (size_t)d * Hn * 320, elog);
    k_gat4<<<dim3(Bn, Hn), 256, 0, stream>>>(
        h_bf, elog, eidx, a_gat + (size_t)d * Hn * 320, b_gat + d * Hn, att_bf);
    k_gru_mfma3<<<512, 512, 0, stream>>>(
        att_bf, nup_bf, Wt_gru + (size_t)d * 768 * 512, b_gru + d * 3 * Un,
        nodes_bf);
    __hip_bfloat16* t = ein; ein = eout; eout = t;
  }
  k_pool<<<Bn, 256, 0, stream>>>(nodes_bf, W_p1, b_p1, W_p2, b_p2, (float*)d_out);
}